// Round 6
// baseline (170.947 us; speedup 1.0000x reference)
//
#include <hip/hip_runtime.h>
#include <math.h>

#define BATCH 8
#define T 2048
#define H 1024
#define D 64

typedef __attribute__((ext_vector_type(8))) short bf16x8;
typedef __attribute__((ext_vector_type(4))) short bf16x4;
typedef __attribute__((ext_vector_type(4))) float f32x4;

__device__ __forceinline__ short f2bf(float f) {
  union { float f; unsigned u; } x; x.f = f;
  return (short)((x.u + 0x7FFFu + ((x.u >> 16) & 1u)) >> 16);
}

#define MFMA(a, b, c) __builtin_amdgcn_mfma_f32_16x16x32_bf16(a, b, c, 0, 0, 0)

// 16x16x16 bf16 MFMA (P^T is born in its B-operand layout). Host pass sees
// neither builtin -> shuffle fallback (parses everywhere; NO #error).
#if __has_builtin(__builtin_amdgcn_mfma_f32_16x16x16bf16_1k)
#define MFMA16(a, b, c) __builtin_amdgcn_mfma_f32_16x16x16bf16_1k(a, b, c, 0, 0, 0)
#define HAVE_MFMA16 1
#elif __has_builtin(__builtin_amdgcn_mfma_f32_16x16x16_bf16)
#define MFMA16(a, b, c) __builtin_amdgcn_mfma_f32_16x16x16_bf16(a, b, c, 0, 0, 0)
#define HAVE_MFMA16 1
#else
#define HAVE_MFMA16 0
#endif

// ---------------------------------------------------------------------------
// Kernel 1: W [1024][64] fp32 -> Wt[3][64 n][1024 k] bf16 (transposed).
// which 0 = Wq (pre-scaled by 0.125*log2e so attention uses exp2 directly).
// ---------------------------------------------------------------------------
__global__ __launch_bounds__(256) void prep_w(
    const float* __restrict__ Wq, const float* __restrict__ Wk,
    const float* __restrict__ Wv, short* __restrict__ Wt) {
  const int which = blockIdx.y;
  const float* W = which == 0 ? Wq : which == 1 ? Wk : Wv;
  const float scale = which == 0 ? 0.125f * 1.44269504088896340736f : 1.0f;
  const int kbase = blockIdx.x * 64;
  const int n = threadIdx.x & 63;
  const int k0 = threadIdx.x >> 6;
  short* dst = Wt + (size_t)which * (D * H);
#pragma unroll
  for (int i = 0; i < 16; ++i) {
    int k = kbase + i * 4 + k0;
    dst[n * H + k] = f2bf(W[(size_t)k * D + n] * scale);
  }
}

// ---------------------------------------------------------------------------
// Kernel 2: q/k/v projection GEMM. M-tile 32, grid 512 (2 blocks/CU).
// B-fragments load DIRECT from global (Wt is 384 KB -> L2-resident; no Bs
// LDS at all). As double-buffered (2x4.6 KB), one barrier per k-iter.
// Wave wv owns n-frags gnt = wv*3..wv*3+2 (unique -> no duplicate B loads)
// and both m-frags: 12 MFMA vs 4 ds_read_b128 per wave-iter.
// ---------------------------------------------------------------------------
__global__ __launch_bounds__(256) void proj_mfma(
    const float* __restrict__ x, const short* __restrict__ Wt,
    short* __restrict__ qb, short* __restrict__ kb, short* __restrict__ vT) {
  __shared__ short As[2][32][72];
  const int mbase = blockIdx.x * 32;
  const int tid = threadIdx.x;
  const int lane = tid & 63, wv = tid >> 6;
  const int l15 = lane & 15, quad = lane >> 4;
  const int ra = tid >> 3, ca = (tid & 7) * 8;  // stage: row 0..31, col 8-float chunk

  const float* xrow = x + (size_t)(mbase + ra) * H + ca;

  // prologue: tile 0 regs
  float4 xr0 = *(const float4*)(xrow);
  float4 xr1 = *(const float4*)(xrow + 4);

  f32x4 acc[2][3] = {};  // [m-frag][n-frag]

  const short* wbase[3];
#pragma unroll
  for (int nt = 0; nt < 3; ++nt) {
    const int gnt = wv * 3 + nt;
    wbase[nt] = Wt + (size_t)(gnt >> 2) * (D * H) + (size_t)((gnt & 3) * 16 + l15) * H;
  }

  // stage tile 0
  {
    bf16x8 p;
    p[0] = f2bf(xr0.x); p[1] = f2bf(xr0.y); p[2] = f2bf(xr0.z); p[3] = f2bf(xr0.w);
    p[4] = f2bf(xr1.x); p[5] = f2bf(xr1.y); p[6] = f2bf(xr1.z); p[7] = f2bf(xr1.w);
    *(bf16x8*)&As[0][ra][ca] = p;
  }
  __syncthreads();

  for (int i = 0; i < 16; ++i) {
    const int cur = i & 1;
    if (i + 1 < 16) {  // prefetch next x tile into regs (overlaps compute)
      xr0 = *(const float4*)(xrow + (i + 1) * 64);
      xr1 = *(const float4*)(xrow + (i + 1) * 64 + 4);
    }
#pragma unroll
    for (int kk = 0; kk < 2; ++kk) {
      bf16x8 a0 = *(const bf16x8*)&As[cur][l15][kk * 32 + quad * 8];
      bf16x8 a1 = *(const bf16x8*)&As[cur][16 + l15][kk * 32 + quad * 8];
#pragma unroll
      for (int nt = 0; nt < 3; ++nt) {
        bf16x8 bfr = *(const bf16x8*)(wbase[nt] + i * 64 + kk * 32 + quad * 8);
        acc[0][nt] = MFMA(a0, bfr, acc[0][nt]);
        acc[1][nt] = MFMA(a1, bfr, acc[1][nt]);
      }
    }
    if (i + 1 < 16) {
      bf16x8 p;
      p[0] = f2bf(xr0.x); p[1] = f2bf(xr0.y); p[2] = f2bf(xr0.z); p[3] = f2bf(xr0.w);
      p[4] = f2bf(xr1.x); p[5] = f2bf(xr1.y); p[6] = f2bf(xr1.z); p[7] = f2bf(xr1.w);
      *(bf16x8*)&As[cur ^ 1][ra][ca] = p;
    }
    __syncthreads();
  }

  // epilogue: row = mbase + mt*16 + quad*4 + r; col = (gnt&3)*16 + l15
#pragma unroll
  for (int nt = 0; nt < 3; ++nt) {
    const int gnt = wv * 3 + nt;
    const int w3 = gnt >> 2;
    const int d = (gnt & 3) * 16 + l15;
#pragma unroll
    for (int mt = 0; mt < 2; ++mt) {
      const int row0 = mbase + mt * 16 + quad * 4;
      if (w3 < 2) {
        short* dst = (w3 == 0) ? qb : kb;
#pragma unroll
        for (int r = 0; r < 4; ++r)
          dst[(size_t)(row0 + r) * D + d] = f2bf(acc[mt][nt][r]);
      } else {
        const int bb = row0 >> 11, t0 = row0 & 2047;
        short4 pk = make_short4(f2bf(acc[mt][nt][0]), f2bf(acc[mt][nt][1]),
                                f2bf(acc[mt][nt][2]), f2bf(acc[mt][nt][3]));
        *(short4*)(vT + ((size_t)(bb * D + d)) * T + t0) = pk;
      }
    }
  }
}

// ---------------------------------------------------------------------------
// Kernel 3: paired causal flash attention — NO split-K, NO combine.
// Block (b, p) owns 32-row q-tiles qtA=p (waves 0-1) and qtB=63-p (waves
// 2-3). Key tiles staged ONCE serve both (A's keys are a prefix of B's).
// Every block does exactly 33 tile-compute units -> perfect causal balance.
// Double-buffered K/V tiles, one barrier per tile. S^T = K Q^T; P^T feeds
// O^T = V^T P^T from registers (C/D layout == 16x16x16 B-operand layout).
// ---------------------------------------------------------------------------
__global__ __launch_bounds__(256) void attn_pair(
    const short* __restrict__ qbuf, const short* __restrict__ kbuf,
    const short* __restrict__ vT, float* __restrict__ out) {
  __shared__ short Ks[2][64][72];
  __shared__ short Vs[2][64][72];

  const int g = blockIdx.x;
  const int b = g >> 5;   // 0..7
  const int p = g & 31;   // pair index: q-tiles p and 63-p (32-row tiles)

  const int tid = threadIdx.x;
  const int lane = tid & 63, wv = tid >> 6;
  const int l15 = lane & 15, quad = lane >> 4;

  const int qt = (wv < 2) ? p : (63 - p);
  const int kA = (p + 2) >> 1;              // key tiles for q-tile p
  const int kB = (2111 - 32 * p) >> 6;      // key tiles for q-tile 63-p (17..32)
  const int kOwn = (wv < 2) ? kA : kB;
  const int qrow = qt * 32 + (wv & 1) * 16 + l15;

  const short* qp = qbuf + (size_t)(b * T + qrow) * D;
  bf16x8 qf0 = *(const bf16x8*)(qp + quad * 8);
  bf16x8 qf1 = *(const bf16x8*)(qp + 32 + quad * 8);

  const int srow = tid >> 2, soff = (tid & 3) * 16;
  const short* kbb = kbuf + (size_t)b * T * D;
  const short* vbb = vT + (size_t)b * D * T;

  f32x4 o[4] = {};
  float lsum = 0.f;

  // prologue: tile 0 -> buf 0
  bf16x8 kr0, kr1, vr0, vr1;
  {
    const bf16x8* kp = (const bf16x8*)(kbb + (size_t)srow * D + soff);
    kr0 = kp[0]; kr1 = kp[1];
    const bf16x8* vp = (const bf16x8*)(vbb + (size_t)srow * T + soff);
    vr0 = vp[0]; vr1 = vp[1];
  }
  *(bf16x8*)&Ks[0][srow][soff] = kr0; *(bf16x8*)&Ks[0][srow][soff + 8] = kr1;
  *(bf16x8*)&Vs[0][srow][soff] = vr0; *(bf16x8*)&Vs[0][srow][soff + 8] = vr1;
  __syncthreads();

  for (int i = 0; i < kB; ++i) {
    const int cur = i & 1;
    if (i + 1 < kB) {  // global -> regs for tile i+1 (overlaps compute)
      const bf16x8* kp = (const bf16x8*)(kbb + (size_t)((i + 1) * 64 + srow) * D + soff);
      kr0 = kp[0]; kr1 = kp[1];
      const bf16x8* vp = (const bf16x8*)(vbb + (size_t)srow * T + (i + 1) * 64 + soff);
      vr0 = vp[0]; vr1 = vp[1];
    }

    if (i < kOwn) {
      // S^T = K Q^T (log2 domain: q pre-scaled by 0.125*log2e)
      f32x4 s[4] = {};
#pragma unroll
      for (int nt = 0; nt < 4; ++nt) {
        bf16x8 ka0 = *(const bf16x8*)&Ks[cur][nt * 16 + l15][quad * 8];
        bf16x8 ka1 = *(const bf16x8*)&Ks[cur][nt * 16 + l15][32 + quad * 8];
        s[nt] = MFMA(ka1, qf1, MFMA(ka0, qf0, s[nt]));
      }
      const bool diag = (i == kOwn - 1);  // only the last tile can cross qrow
#pragma unroll
      for (int nt = 0; nt < 4; ++nt) {
#pragma unroll
        for (int r = 0; r < 4; ++r) {
          float pv = exp2f(s[nt][r]);
          if (diag) {
            int key = i * 64 + nt * 16 + quad * 4 + r;
            if (key > qrow) pv = 0.f;
          }
          lsum += pv;
          s[nt][r] = pv;
        }
      }
#if HAVE_MFMA16
#pragma unroll
      for (int nt = 0; nt < 4; ++nt) {
        bf16x4 pb;
        pb[0] = f2bf(s[nt][0]); pb[1] = f2bf(s[nt][1]);
        pb[2] = f2bf(s[nt][2]); pb[3] = f2bf(s[nt][3]);
#pragma unroll
        for (int dt = 0; dt < 4; ++dt) {
          bf16x4 va = *(const bf16x4*)&Vs[cur][dt * 16 + l15][nt * 16 + quad * 4];
          o[dt] = MFMA16(va, pb, o[dt]);
        }
      }
#else
      // In-wave shuffle gather of 16x16x32 B-frags (R3-verified mapping).
#pragma unroll
      for (int h = 0; h < 2; ++h) {
        union { short2 s2; int i2; } a01, a23, b01, b23;
        a01.s2 = make_short2(f2bf(s[2 * h][0]), f2bf(s[2 * h][1]));
        a23.s2 = make_short2(f2bf(s[2 * h][2]), f2bf(s[2 * h][3]));
        b01.s2 = make_short2(f2bf(s[2 * h + 1][0]), f2bf(s[2 * h + 1][1]));
        b23.s2 = make_short2(f2bf(s[2 * h + 1][2]), f2bf(s[2 * h + 1][3]));
        const int srcA = l15 + ((quad & 1) << 5);
        const int srcB = srcA + 16;
        int gA01 = __shfl(a01.i2, srcA), gA01b = __shfl(b01.i2, srcA);
        int gA23 = __shfl(a23.i2, srcA), gA23b = __shfl(b23.i2, srcA);
        int gB01 = __shfl(a01.i2, srcB), gB01b = __shfl(b01.i2, srcB);
        int gB23 = __shfl(a23.i2, srcB), gB23b = __shfl(b23.i2, srcB);
        union { int d[4]; bf16x8 v; } pf;
        const bool lo = (quad < 2);
        pf.d[0] = lo ? gA01 : gA01b;
        pf.d[1] = lo ? gA23 : gA23b;
        pf.d[2] = lo ? gB01 : gB01b;
        pf.d[3] = lo ? gB23 : gB23b;
#pragma unroll
        for (int dt = 0; dt < 4; ++dt) {
          bf16x8 va = *(const bf16x8*)&Vs[cur][dt * 16 + l15][h * 32 + quad * 8];
          o[dt] = MFMA(va, pf.v, o[dt]);
        }
      }
#endif
    }

    if (i + 1 < kB) {  // LDS-write tile i+1 into the other buffer
      *(bf16x8*)&Ks[cur ^ 1][srow][soff] = kr0;
      *(bf16x8*)&Ks[cur ^ 1][srow][soff + 8] = kr1;
      *(bf16x8*)&Vs[cur ^ 1][srow][soff] = vr0;
      *(bf16x8*)&Vs[cur ^ 1][srow][soff + 8] = vr1;
    }
    __syncthreads();
  }

  // row-sum across quads (lane bits 4..5), then normalize + write O^T
  float lv = lsum;
  lv += __shfl_xor(lv, 16);
  lv += __shfl_xor(lv, 32);
  const float inv = 1.0f / lv;
  float* op = out + (size_t)(b * T + qrow) * D;
#pragma unroll
  for (int dt = 0; dt < 4; ++dt)
    *(float4*)(op + dt * 16 + quad * 4) =
        make_float4(o[dt][0] * inv, o[dt][1] * inv, o[dt][2] * inv, o[dt][3] * inv);
}

// ---------------------------------------------------------------------------
extern "C" void kernel_launch(void* const* d_in, const int* in_sizes, int n_in,
                              void* d_out, int out_size, void* d_ws, size_t ws_size,
                              hipStream_t stream) {
  const float* x  = (const float*)d_in[0];
  const float* Wk = (const float*)d_in[1];
  const float* Wq = (const float*)d_in[2];
  const float* Wv = (const float*)d_in[3];
  float* out = (float*)d_out;

  const size_t M = (size_t)BATCH * T * D;  // 1,048,576 elements
  short* qb = (short*)d_ws;                // 2 MB
  short* kb = qb + M;                      // 2 MB
  short* vT = kb + M;                      // 2 MB
  short* Wt = vT + M;                      // 384 KB  (12.4 MB total ws use)

  prep_w<<<dim3(16, 3), 256, 0, stream>>>(Wq, Wk, Wv, Wt);
  proj_mfma<<<dim3(512), 256, 0, stream>>>(x, Wt, qb, kb, vT);
  attn_pair<<<dim3(256), 256, 0, stream>>>(qb, kb, vT, out);
}

// Round 7
// 141.158 us; speedup vs baseline: 1.2110x; 1.2110x over previous
//
#include <hip/hip_runtime.h>
#include <math.h>

#define BATCH 8
#define T 2048
#define H 1024
#define D 64

typedef __attribute__((ext_vector_type(8))) short bf16x8;
typedef __attribute__((ext_vector_type(4))) short bf16x4;
typedef __attribute__((ext_vector_type(4))) float f32x4;

__device__ __forceinline__ short f2bf(float f) {
  union { float f; unsigned u; } x; x.f = f;
  return (short)((x.u + 0x7FFFu + ((x.u >> 16) & 1u)) >> 16);
}

#define MFMA(a, b, c) __builtin_amdgcn_mfma_f32_16x16x32_bf16(a, b, c, 0, 0, 0)

// 16x16x16 bf16 MFMA (P^T is born in its B-operand layout). Host pass sees
// neither builtin -> shuffle fallback (parses everywhere; NO #error).
#if __has_builtin(__builtin_amdgcn_mfma_f32_16x16x16bf16_1k)
#define MFMA16(a, b, c) __builtin_amdgcn_mfma_f32_16x16x16bf16_1k(a, b, c, 0, 0, 0)
#define HAVE_MFMA16 1
#elif __has_builtin(__builtin_amdgcn_mfma_f32_16x16x16_bf16)
#define MFMA16(a, b, c) __builtin_amdgcn_mfma_f32_16x16x16_bf16(a, b, c, 0, 0, 0)
#define HAVE_MFMA16 1
#else
#define HAVE_MFMA16 0
#endif

#define NCHUNK_MAX 11  // ceil(32/3) chunks of 3 k-tiles

// ---------------------------------------------------------------------------
// Kernel 1: W [1024][64] fp32 -> Wt[3][64 n][1024 k] bf16 (transposed).
// which 0 = Wq (pre-scaled by 0.125*log2e so attention uses exp2 directly).
// ---------------------------------------------------------------------------
__global__ __launch_bounds__(256) void prep_w(
    const float* __restrict__ Wq, const float* __restrict__ Wk,
    const float* __restrict__ Wv, short* __restrict__ Wt) {
  const int which = blockIdx.y;
  const float* W = which == 0 ? Wq : which == 1 ? Wk : Wv;
  const float scale = which == 0 ? 0.125f * 1.44269504088896340736f : 1.0f;
  const int kbase = blockIdx.x * 64;
  const int n = threadIdx.x & 63;
  const int k0 = threadIdx.x >> 6;
  short* dst = Wt + (size_t)which * (D * H);
#pragma unroll
  for (int i = 0; i < 16; ++i) {
    int k = kbase + i * 4 + k0;
    dst[n * H + k] = f2bf(W[(size_t)k * D + n] * scale);
  }
}

// ---------------------------------------------------------------------------
// Kernel 2: q/k/v projection GEMM. 32-row M-tile -> grid 512 = 2 blocks/CU
// (R5's 64-tile grid 256 = 1 block/CU was barrier-latency bound at 4
// waves/CU: MfmaUtil 4.7, VALUBusy 5.4, HBM 11% — nothing busy).
// A and B both double-buffered in LDS (64.5 KB total, x2 blocks = 129 KB
// < 160 KB/CU): ONE barrier per k-iter, two blocks interleave at barriers.
// Per wave-iter: 12 MFMA vs 10 ds_read_b128.
// ---------------------------------------------------------------------------
__global__ __launch_bounds__(256) void proj_mfma(
    const float* __restrict__ x, const short* __restrict__ Wt,
    short* __restrict__ qb, short* __restrict__ kb, short* __restrict__ vT) {
  __shared__ short As[2][32][72];      //  9216 B
  __shared__ short Bs[2][3][64][72];   // 55296 B
  const int mbase = blockIdx.x * 32;
  const int tid = threadIdx.x;
  const int lane = tid & 63, wv = tid >> 6;
  const int l15 = lane & 15, quad = lane >> 4;

  // staging coords: A = 32 rows x 64 cols, B = 3 x (64 rows x 64 cols)
  const int ra = tid >> 3, ca = (tid & 7) * 8;   // A: 8 fp32 per thread
  const int rb = tid >> 2, cb = (tid & 3) * 16;  // B: 16 bf16 per thread

  const float* xrow = x + (size_t)(mbase + ra) * H + ca;
  const short* wsrc[3];
#pragma unroll
  for (int w3 = 0; w3 < 3; ++w3)
    wsrc[w3] = Wt + (size_t)w3 * (D * H) + (size_t)rb * H + cb;

  // prologue: tile 0 -> regs -> LDS buf 0
  float4 xr0 = *(const float4*)(xrow);
  float4 xr1 = *(const float4*)(xrow + 4);
  bf16x8 wr[3][2];
#pragma unroll
  for (int w3 = 0; w3 < 3; ++w3) {
    wr[w3][0] = *(const bf16x8*)(wsrc[w3]);
    wr[w3][1] = *(const bf16x8*)(wsrc[w3] + 8);
  }
  {
    bf16x8 p;
    p[0] = f2bf(xr0.x); p[1] = f2bf(xr0.y); p[2] = f2bf(xr0.z); p[3] = f2bf(xr0.w);
    p[4] = f2bf(xr1.x); p[5] = f2bf(xr1.y); p[6] = f2bf(xr1.z); p[7] = f2bf(xr1.w);
    *(bf16x8*)&As[0][ra][ca] = p;
#pragma unroll
    for (int w3 = 0; w3 < 3; ++w3) {
      *(bf16x8*)&Bs[0][w3][rb][cb] = wr[w3][0];
      *(bf16x8*)&Bs[0][w3][rb][cb + 8] = wr[w3][1];
    }
  }
  __syncthreads();

  f32x4 acc[2][3] = {};  // [m-frag][n-frag]

  for (int i = 0; i < 16; ++i) {
    const int cur = i & 1;
    if (i + 1 < 16) {  // issue next tile's global loads (overlap compute)
      xr0 = *(const float4*)(xrow + (i + 1) * 64);
      xr1 = *(const float4*)(xrow + (i + 1) * 64 + 4);
#pragma unroll
      for (int w3 = 0; w3 < 3; ++w3) {
        wr[w3][0] = *(const bf16x8*)(wsrc[w3] + (i + 1) * 64);
        wr[w3][1] = *(const bf16x8*)(wsrc[w3] + (i + 1) * 64 + 8);
      }
    }
#pragma unroll
    for (int kk = 0; kk < 2; ++kk) {
      bf16x8 a0 = *(const bf16x8*)&As[cur][l15][kk * 32 + quad * 8];
      bf16x8 a1 = *(const bf16x8*)&As[cur][16 + l15][kk * 32 + quad * 8];
#pragma unroll
      for (int nt = 0; nt < 3; ++nt) {
        const int gnt = wv * 3 + nt;
        bf16x8 b =
            *(const bf16x8*)&Bs[cur][gnt >> 2][(gnt & 3) * 16 + l15][kk * 32 + quad * 8];
        acc[0][nt] = MFMA(a0, b, acc[0][nt]);
        acc[1][nt] = MFMA(a1, b, acc[1][nt]);
      }
    }
    if (i + 1 < 16) {  // write next tile into the other buffer
      bf16x8 p;
      p[0] = f2bf(xr0.x); p[1] = f2bf(xr0.y); p[2] = f2bf(xr0.z); p[3] = f2bf(xr0.w);
      p[4] = f2bf(xr1.x); p[5] = f2bf(xr1.y); p[6] = f2bf(xr1.z); p[7] = f2bf(xr1.w);
      *(bf16x8*)&As[cur ^ 1][ra][ca] = p;
#pragma unroll
      for (int w3 = 0; w3 < 3; ++w3) {
        *(bf16x8*)&Bs[cur ^ 1][w3][rb][cb] = wr[w3][0];
        *(bf16x8*)&Bs[cur ^ 1][w3][rb][cb + 8] = wr[w3][1];
      }
    }
    __syncthreads();
  }

  // epilogue: row = mbase + mt*16 + quad*4 + r; col = (gnt&3)*16 + l15
#pragma unroll
  for (int nt = 0; nt < 3; ++nt) {
    const int gnt = wv * 3 + nt;
    const int w3 = gnt >> 2;
    const int d = (gnt & 3) * 16 + l15;
#pragma unroll
    for (int mt = 0; mt < 2; ++mt) {
      const int row0 = mbase + mt * 16 + quad * 4;
      if (w3 < 2) {
        short* dst = (w3 == 0) ? qb : kb;
#pragma unroll
        for (int r = 0; r < 4; ++r)
          dst[(size_t)(row0 + r) * D + d] = f2bf(acc[mt][nt][r]);
      } else {
        const int bb = row0 >> 11, t0 = row0 & 2047;
        short4 pk = make_short4(f2bf(acc[mt][nt][0]), f2bf(acc[mt][nt][1]),
                                f2bf(acc[mt][nt][2]), f2bf(acc[mt][nt][3]));
        *(short4*)(vT + ((size_t)(bb * D + d)) * T + t0) = pk;
      }
    }
  }
}

// ---------------------------------------------------------------------------
// Kernel 3: transposed flash attention, split-K, whole-chunk staging
// (R5-verified: grid 1496, chunk = 3 k-tiles, one barrier per chunk).
// S^T = K Q^T; P^T feeds O^T = V^T P^T from registers.
// ---------------------------------------------------------------------------
__global__ __launch_bounds__(256) void attn_mfma(
    const short* __restrict__ qbuf, const short* __restrict__ kbuf,
    const short* __restrict__ vT, float* __restrict__ out,
    float* __restrict__ Opart, float* __restrict__ lpart, int mode) {
  __shared__ short Ks[192][72];   // 27648 B
  __shared__ short Vs[64][200];   // 25600 B  (total 53248 B)

  const int g = blockIdx.x;
  int b, qt, c;
  if (mode == 0) {
    b = g >> 5; qt = g & 31; c = 0;
  } else {
    b = g / 187;
    int r = g - b * 187;
    qt = 0; c = 0;
    for (int gg = 0;; ++gg) {
      const int cnt = (gg < 10) ? 3 * (gg + 1) : 22;
      if (r < cnt) { qt = 3 * gg + r / (gg + 1); c = r - (r / (gg + 1)) * (gg + 1); break; }
      r -= cnt;
    }
  }
  const int kt0 = c * 3;
  const int kt1 = (mode == 0) ? (qt + 1) : min(kt0 + 3, qt + 1);

  const int tid = threadIdx.x;
  const int lane = tid & 63, wv = tid >> 6;
  const int l15 = lane & 15, quad = lane >> 4;
  const int qrow = qt * 64 + wv * 16 + l15;

  const short* qp = qbuf + (size_t)(b * T + qrow) * D;
  bf16x8 qf0 = *(const bf16x8*)(qp + quad * 8);
  bf16x8 qf1 = *(const bf16x8*)(qp + 32 + quad * 8);

  const int srow = tid >> 2, soff = (tid & 3) * 16;
  const short* kbb = kbuf + (size_t)b * T * D;
  const short* vbb = vT + (size_t)b * D * T;

  f32x4 o[4] = {};
  float lsum = 0.f;

  for (int base = kt0; base < kt1; base += 3) {
    const int nt3 = min(3, kt1 - base);
    if (base > kt0) __syncthreads();
    for (int t3 = 0; t3 < nt3; ++t3) {
      const bf16x8* kp = (const bf16x8*)(kbb + (size_t)((base + t3) * 64 + srow) * D + soff);
      bf16x8 k0 = kp[0], k1 = kp[1];
      const bf16x8* vp = (const bf16x8*)(vbb + (size_t)srow * T + (base + t3) * 64 + soff);
      bf16x8 v0 = vp[0], v1 = vp[1];
      *(bf16x8*)&Ks[t3 * 64 + srow][soff] = k0;
      *(bf16x8*)&Ks[t3 * 64 + srow][soff + 8] = k1;
      *(bf16x8*)&Vs[srow][t3 * 64 + soff] = v0;
      *(bf16x8*)&Vs[srow][t3 * 64 + soff + 8] = v1;
    }
    __syncthreads();

    for (int tt = 0; tt < nt3; ++tt) {
      const int kt = base + tt;
      f32x4 s[4] = {};
#pragma unroll
      for (int nt = 0; nt < 4; ++nt) {
        bf16x8 ka0 = *(const bf16x8*)&Ks[tt * 64 + nt * 16 + l15][quad * 8];
        bf16x8 ka1 = *(const bf16x8*)&Ks[tt * 64 + nt * 16 + l15][32 + quad * 8];
        s[nt] = MFMA(ka1, qf1, MFMA(ka0, qf0, s[nt]));
      }
      const bool diag = (kt == qt);
#pragma unroll
      for (int nt = 0; nt < 4; ++nt) {
#pragma unroll
        for (int r = 0; r < 4; ++r) {
          float p = exp2f(s[nt][r]);
          if (diag) {
            int key = kt * 64 + nt * 16 + quad * 4 + r;
            if (key > qrow) p = 0.f;
          }
          lsum += p;
          s[nt][r] = p;
        }
      }
#if HAVE_MFMA16
#pragma unroll
      for (int nt = 0; nt < 4; ++nt) {
        bf16x4 pb;
        pb[0] = f2bf(s[nt][0]); pb[1] = f2bf(s[nt][1]);
        pb[2] = f2bf(s[nt][2]); pb[3] = f2bf(s[nt][3]);
#pragma unroll
        for (int dt = 0; dt < 4; ++dt) {
          bf16x4 va = *(const bf16x4*)&Vs[dt * 16 + l15][tt * 64 + nt * 16 + quad * 4];
          o[dt] = MFMA16(va, pb, o[dt]);
        }
      }
#else
#pragma unroll
      for (int h = 0; h < 2; ++h) {
        union { short2 s2; int i2; } a01, a23, b01, b23;
        a01.s2 = make_short2(f2bf(s[2 * h][0]), f2bf(s[2 * h][1]));
        a23.s2 = make_short2(f2bf(s[2 * h][2]), f2bf(s[2 * h][3]));
        b01.s2 = make_short2(f2bf(s[2 * h + 1][0]), f2bf(s[2 * h + 1][1]));
        b23.s2 = make_short2(f2bf(s[2 * h + 1][2]), f2bf(s[2 * h + 1][3]));
        const int srcA = l15 + ((quad & 1) << 5);
        const int srcB = srcA + 16;
        int gA01 = __shfl(a01.i2, srcA), gA01b = __shfl(b01.i2, srcA);
        int gA23 = __shfl(a23.i2, srcA), gA23b = __shfl(b23.i2, srcA);
        int gB01 = __shfl(a01.i2, srcB), gB01b = __shfl(b01.i2, srcB);
        int gB23 = __shfl(a23.i2, srcB), gB23b = __shfl(b23.i2, srcB);
        union { int d[4]; bf16x8 v; } pf;
        const bool lo = (quad < 2);
        pf.d[0] = lo ? gA01 : gA01b;
        pf.d[1] = lo ? gA23 : gA23b;
        pf.d[2] = lo ? gB01 : gB01b;
        pf.d[3] = lo ? gB23 : gB23b;
#pragma unroll
        for (int dt = 0; dt < 4; ++dt) {
          bf16x8 va = *(const bf16x8*)&Vs[dt * 16 + l15][tt * 64 + h * 32 + quad * 8];
          o[dt] = MFMA(va, pf.v, o[dt]);
        }
      }
#endif
    }
  }

  float lv = lsum;
  lv += __shfl_xor(lv, 16);
  lv += __shfl_xor(lv, 32);

  if (kt0 == 0 && kt1 == qt + 1) {
    const float inv = 1.0f / lv;
    float* op = out + (size_t)(b * T + qrow) * D;
#pragma unroll
    for (int dt = 0; dt < 4; ++dt)
      *(float4*)(op + dt * 16 + quad * 4) =
          make_float4(o[dt][0] * inv, o[dt][1] * inv, o[dt][2] * inv, o[dt][3] * inv);
  } else {
    const int prow = b * T + qrow;
    float* pp = Opart + ((size_t)c * 16384 + prow) * D;
#pragma unroll
    for (int dt = 0; dt < 4; ++dt)
      *(float4*)(pp + dt * 16 + quad * 4) =
          make_float4(o[dt][0], o[dt][1], o[dt][2], o[dt][3]);
    if (quad == 0) lpart[c * 16384 + prow] = lv;
  }
}

// ---------------------------------------------------------------------------
// Kernel 4: combine split-K partials for rows with >=2 chunks (qrow >= 192).
// ---------------------------------------------------------------------------
__global__ __launch_bounds__(256) void combine_k(
    const float* __restrict__ Opart, const float* __restrict__ lpart,
    float* __restrict__ out) {
  const int gid = blockIdx.x * 256 + threadIdx.x;  // 928*256 = 237568
  const int r16 = gid >> 4;                        // 0..14847
  const int b = r16 / 1856;
  const int qrow = 192 + (r16 - b * 1856);
  const int row = b * T + qrow;
  const int d4 = (gid & 15) << 2;
  const int nc = (qrow >> 6) / 3 + 1;  // 2..11 chunks
  float a0 = 0.f, a1 = 0.f, a2 = 0.f, a3 = 0.f, l = 0.f;
  for (int c = 0; c < nc; ++c) {
    const float4 t = *(const float4*)(Opart + ((size_t)c * 16384 + row) * D + d4);
    a0 += t.x; a1 += t.y; a2 += t.z; a3 += t.w;
    l += lpart[c * 16384 + row];
  }
  const float inv = 1.0f / l;
  *(float4*)(out + (size_t)row * D + d4) = make_float4(a0 * inv, a1 * inv, a2 * inv, a3 * inv);
}

// ---------------------------------------------------------------------------
extern "C" void kernel_launch(void* const* d_in, const int* in_sizes, int n_in,
                              void* d_out, int out_size, void* d_ws, size_t ws_size,
                              hipStream_t stream) {
  const float* x  = (const float*)d_in[0];
  const float* Wk = (const float*)d_in[1];
  const float* Wq = (const float*)d_in[2];
  const float* Wv = (const float*)d_in[3];
  float* out = (float*)d_out;

  const size_t M = (size_t)BATCH * T * D;  // 1,048,576 elements
  short* qb = (short*)d_ws;
  short* kb = qb + M;
  short* vT = kb + M;
  short* Wt = vT + M;                       // 196,608 shorts
  float* Opart = (float*)(Wt + 196608);
  float* lpart = Opart + (size_t)NCHUNK_MAX * 16384 * 64;

  const size_t need = (3 * M + 196608) * 2 +
                      ((size_t)NCHUNK_MAX * 16384 * 64 + (size_t)NCHUNK_MAX * 16384) * 4;
  const bool split = ws_size >= need;

  prep_w<<<dim3(16, 3), 256, 0, stream>>>(Wq, Wk, Wv, Wt);
  proj_mfma<<<dim3(512), 256, 0, stream>>>(x, Wt, qb, kb, vT);
  if (split) {
    attn_mfma<<<dim3(1496), 256, 0, stream>>>(qb, kb, vT, out, Opart, lpart, 1);
    combine_k<<<dim3(928), 256, 0, stream>>>(Opart, lpart, out);
  } else {
    attn_mfma<<<dim3(256), 256, 0, stream>>>(qb, kb, vT, out, Opart, lpart, 0);
  }
}